// Round 1
// baseline (509.703 us; speedup 1.0000x reference)
//
#include <hip/hip_runtime.h>
#include <hip/hip_fp16.h>

// Problem constants
#define N_BATCH 8
#define CI 8
#define CO 16
#define IDHW 64
#define ODIM 66
#define OSP (66*66*66)        // 287496 per (n, co) slab
#define GROUPS 4

// Pass-1 tile constants
#define ROWS 8                 // oh rows per block
#define SEGS 8                 // ow segments
#define SEGW 9                 // ow per thread (8*9=72 >= 66)
#define XW 76                  // LDS x row width (indices 0..73 used)
#define XROWS 10               // oh rows + 2 halo
#define XLDS (3*XROWS*XW)      // 2280 floats per ci
#define NTHR 256

// ws layout (floats): [0..31] sum, [32..63] sumsq, [64..95] mean, [96..127] rstd
__global__ __launch_bounds__(64) void zero_stats(float* ws) {
    ws[threadIdx.x] = 0.0f;
}

__global__ __launch_bounds__(NTHR) void conv_relu_stats(
    const float* __restrict__ x, const float* __restrict__ w,
    float* __restrict__ out, float* __restrict__ stats)
{
    __shared__ float w_lds[216 * 16];     // 13824 B: [ci*27+k][co]
    __shared__ float x_lds[XLDS];         // 9120 B:  [dz][row][iw+2]
    __shared__ float reds[2][4][4];       // [sum/ss][wave][cg]

    const int tid = threadIdx.x;
    const int n   = blockIdx.z;
    const int od  = blockIdx.y;
    const int oh0 = blockIdx.x * ROWS;

    // Stage weights once, with the reference's fp16 round-trip quantization.
    // Layout [idx][co] so a thread's 4 consecutive co are one 16B-aligned float4.
    for (int i = tid; i < 216 * 16; i += NTHR) {
        int idx = i >> 4, co = i & 15;
        int ci = idx / 27, k = idx % 27;
        w_lds[i] = __half2float(__float2half(w[(ci * 16 + co) * 27 + k]));
    }

    const int cg  = tid & 3;        // co quad == groupnorm group
    const int j   = tid >> 2;
    const int seg = j & 7;          // ow segment
    const int row = j >> 3;         // oh row within tile

    float acc[4][SEGW];
    #pragma unroll
    for (int i = 0; i < 4; ++i)
        #pragma unroll
        for (int p = 0; p < SEGW; ++p) acc[i][p] = 0.0f;

    for (int ci = 0; ci < CI; ++ci) {
        __syncthreads();  // protect previous iteration's x_lds reads (and w_lds for ci=0)
        // Stage x tile for this ci: 3 input d-planes x 10 rows x 76 (zero-padded halo)
        for (int i = tid; i < XLDS; i += NTHR) {
            int c    = i % XW;
            int rest = i / XW;
            int r    = rest % XROWS;
            int dz   = rest / XROWS;
            int id = od - 2 + dz;
            int ih = oh0 - 2 + r;
            int iw = c - 2;
            float v = 0.0f;
            if ((unsigned)id < 64u && (unsigned)ih < 64u && (unsigned)iw < 64u)
                v = x[(((size_t)(n * CI + ci) * 64 + id) * 64 + ih) * 64 + iw];
            x_lds[i] = v;
        }
        __syncthreads();

        #pragma unroll
        for (int kd = 0; kd < 3; ++kd) {
            const int dz = 2 - kd;           // id = od - kd
            #pragma unroll
            for (int kh = 0; kh < 3; ++kh) {
                const int rl = row + 2 - kh; // ih = oh - kh
                const float* xp = &x_lds[(dz * XROWS + rl) * XW + seg * SEGW];
                float xw[SEGW + 2];
                #pragma unroll
                for (int c = 0; c < SEGW + 2; ++c) xw[c] = xp[c];
                const int wbase = (((ci * 3 + kd) * 3 + kh) * 3) * 16 + cg * 4;
                #pragma unroll
                for (int kw = 0; kw < 3; ++kw) {
                    const float4 wv = *(const float4*)&w_lds[wbase + kw * 16];
                    #pragma unroll
                    for (int p = 0; p < SEGW; ++p) {
                        const float xv = xw[p + 2 - kw];
                        acc[0][p] = fmaf(wv.x, xv, acc[0][p]);
                        acc[1][p] = fmaf(wv.y, xv, acc[1][p]);
                        acc[2][p] = fmaf(wv.z, xv, acc[2][p]);
                        acc[3][p] = fmaf(wv.w, xv, acc[3][p]);
                    }
                }
            }
        }
    }

    // Epilogue: ReLU, store, per-thread stats (only valid positions)
    float s = 0.0f, ss = 0.0f;
    const int oh = oh0 + row;
    const bool ohok = (oh < ODIM);
    #pragma unroll
    for (int i = 0; i < 4; ++i) {
        const int co = cg * 4 + i;
        float* op = &out[(((size_t)(n * CO + co) * ODIM + od) * ODIM + oh) * ODIM + seg * SEGW];
        #pragma unroll
        for (int p = 0; p < SEGW; ++p) {
            const int ow = seg * SEGW + p;
            if (ohok && ow < ODIM) {
                const float v = fmaxf(acc[i][p], 0.0f);
                op[p] = v;
                s += v;
                ss = fmaf(v, v, ss);
            }
        }
    }

    // Reduce within wave: lanes at distance 4 share the same cg
    s  += __shfl_down(s, 32, 64);  ss += __shfl_down(ss, 32, 64);
    s  += __shfl_down(s, 16, 64);  ss += __shfl_down(ss, 16, 64);
    s  += __shfl_down(s,  8, 64);  ss += __shfl_down(ss,  8, 64);
    s  += __shfl_down(s,  4, 64);  ss += __shfl_down(ss,  4, 64);
    const int wv = tid >> 6, ln = tid & 63;
    if (ln < 4) { reds[0][wv][ln] = s; reds[1][wv][ln] = ss; }
    __syncthreads();
    if (tid < 4) {
        float ts  = reds[0][0][tid] + reds[0][1][tid] + reds[0][2][tid] + reds[0][3][tid];
        float tss = reds[1][0][tid] + reds[1][1][tid] + reds[1][2][tid] + reds[1][3][tid];
        atomicAdd(&stats[n * GROUPS + tid], ts);
        atomicAdd(&stats[32 + n * GROUPS + tid], tss);
    }
}

__global__ __launch_bounds__(64) void finalize_stats(float* ws) {
    const int g = threadIdx.x;
    if (g < 32) {
        const float cnt  = 4.0f * (float)OSP;   // 4 channels per group
        const float mean = ws[g] / cnt;
        const float var  = ws[32 + g] / cnt - mean * mean;
        ws[64 + g] = mean;
        ws[96 + g] = rsqrtf(var + 1e-5f);
    }
}

// In-place normalize: out = (y - mean) * rstd * gamma + beta, float4 per thread
__global__ __launch_bounds__(NTHR) void norm_kernel(
    float* __restrict__ out, const float* __restrict__ ws,
    const float* __restrict__ gamma, const float* __restrict__ beta)
{
    const int slab = blockIdx.y;           // n*16 + co
    const int n  = slab >> 4;
    const int co = slab & 15;
    const int gi = n * GROUPS + (co >> 2);
    const float mean = ws[64 + gi];
    const float rstd = ws[96 + gi];
    const float scale = rstd * gamma[co];
    const float shift = beta[co] - mean * scale;

    const int idx = blockIdx.x * NTHR + threadIdx.x;   // float4 index within slab
    if (idx < OSP / 4) {
        float4* p = (float4*)(out + (size_t)slab * OSP) + idx;
        float4 v = *p;
        v.x = fmaf(v.x, scale, shift);
        v.y = fmaf(v.y, scale, shift);
        v.z = fmaf(v.z, scale, shift);
        v.w = fmaf(v.w, scale, shift);
        *p = v;
    }
}

extern "C" void kernel_launch(void* const* d_in, const int* in_sizes, int n_in,
                              void* d_out, int out_size, void* d_ws, size_t ws_size,
                              hipStream_t stream) {
    const float* x     = (const float*)d_in[0];
    const float* w     = (const float*)d_in[1];
    const float* gamma = (const float*)d_in[2];
    const float* beta  = (const float*)d_in[3];
    float* out = (float*)d_out;
    float* ws  = (float*)d_ws;

    zero_stats<<<1, 64, 0, stream>>>(ws);

    dim3 grid1((ODIM + ROWS - 1) / ROWS, ODIM, N_BATCH);   // (9, 66, 8)
    conv_relu_stats<<<grid1, NTHR, 0, stream>>>(x, w, out, ws);

    finalize_stats<<<1, 64, 0, stream>>>(ws);

    dim3 grid2((OSP / 4 + NTHR - 1) / NTHR, N_BATCH * CO); // (281, 128)
    norm_kernel<<<grid2, NTHR, 0, stream>>>(out, ws, gamma, beta);
}